// Round 19
// baseline (185.806 us; speedup 1.0000x reference)
//
#include <hip/hip_runtime.h>
#include <hip/hip_bf16.h>

// DA block (DANet) — Round 34 (resubmit; R18 bench was an infra failure).
// 2 j-tiles per barrier in k_pbm: 16 phases x 2 tiles, 4 P-buffers pitch 128
// (rotation swizzle handles conflicts) = 65536 B LDS. Phase: QKa,PVa,expa,
// QKb,PVb,expb, prefetch, ONE barrier. Tile/l/acc order identical -> pamT
// bit-identical to R33. All other kernels = R33-green.

#define B_ 2
#define C_ 256
#define N_ 4096
#define QK_ 32

#define TJ_ 128    // j per tile (8 waves x 16)
#define PPB_ 136   // legacy pitch (unused in k_pbm v16)

typedef __hip_bfloat16 bf16;
typedef __attribute__((ext_vector_type(8))) short bf16x8f;   // MFMA A/B frag
typedef __attribute__((ext_vector_type(4))) float f32x4;     // MFMA C/D frag

union bf8pack { bf16 h[8]; int4 v; bf16x8f f; };
union bf4pack { bf16 h[4]; uint2 u; };

// ---- k_wcv: weights -> hi/lo bf16. wqk = [wq;wk] 64x256, wv 256x256 ----
__global__ __launch_bounds__(256) void k_wcv(
    const float* __restrict__ wq, const float* __restrict__ wk, const float* __restrict__ wv,
    bf16* __restrict__ wqkh, bf16* __restrict__ wqkl,
    bf16* __restrict__ wvh, bf16* __restrict__ wvl) {
  int idx = blockIdx.x * 256 + threadIdx.x;
  if (idx < 64 * C_) {
    int r = idx >> 8, c = idx & 255;
    float v = (r < 32) ? wq[r * C_ + c] : wk[(r - 32) * C_ + c];
    bf16 h = __float2bfloat16(v);
    wqkh[idx] = h; wqkl[idx] = __float2bfloat16(v - __bfloat162float(h));
  } else {
    int j = idx - 64 * C_;
    float v = wv[j];
    bf16 h = __float2bfloat16(v);
    wvh[j] = h; wvl[j] = __float2bfloat16(v - __bfloat162float(h));
  }
}

// ---- k_xt v2: x -> xT hi/lo [b][n][c] AND xc hi/lo [b][c][n] ----
__global__ __launch_bounds__(256) void k_xt(
    const float* __restrict__ x, bf16* __restrict__ xthi, bf16* __restrict__ xtlo,
    bf16* __restrict__ xchi, bf16* __restrict__ xclo) {
  int b = blockIdx.z;
  int c0 = blockIdx.y * 64;
  int n0 = blockIdx.x * 64;
  __shared__ float t[64 * 65];
  int tid = threadIdx.x;
  int col = tid & 63, rowq = tid >> 6;        // 4 rows per pass
#pragma unroll
  for (int k = 0; k < 16; k++) {
    int r = k * 4 + rowq;
    size_t src = ((size_t)b * C_ + c0 + r) * N_ + n0 + col;
    float v = x[src];
    t[r * 65 + col] = v;
    bf16 h = __float2bfloat16(v);            // same-layout bf16 hi/lo
    xchi[src] = h;
    xclo[src] = __float2bfloat16(v - __bfloat162float(h));
  }
  __syncthreads();
#pragma unroll
  for (int k = 0; k < 16; k++) {
    int nrow = k * 4 + rowq;
    float v = t[col * 65 + nrow];             // [c_local=col][n_local=nrow]
    bf16 h = __float2bfloat16(v);
    size_t o = ((size_t)b * N_ + n0 + nrow) * C_ + c0 + col;
    xthi[o] = h;
    xtlo[o] = __float2bfloat16(v - __bfloat162float(h));
  }
}

// ---- k_qkp v2: 256 blocks. Wave = 16-o tile x 32 n. Bit-identical q/k ----
__global__ __launch_bounds__(256) void k_qkp(
    const bf16* __restrict__ xthi, const bf16* __restrict__ xtlo,
    const bf16* __restrict__ wqkh, const bf16* __restrict__ wqkl,
    const float* __restrict__ bq, const float* __restrict__ bk,
    bf16* __restrict__ qhi, bf16* __restrict__ qlo,
    bf16* __restrict__ khi, bf16* __restrict__ klo) {
  int b = blockIdx.y;
  int tid = threadIdx.x;
  int lane = tid & 63, wave = tid >> 6;        // wave = o-tile 0..3
  int n16 = lane & 15, quad = lane >> 4;
  int nb = blockIdx.x * 32;

  f32x4 acc[2];                                // [nt]
#pragma unroll
  for (int nt = 0; nt < 2; nt++) acc[nt] = (f32x4)(0.f);

#pragma unroll
  for (int kk = 0; kk < 8; kk++) {
    bf16x8f Ah, Al, Bh[2], Bl[2];
    {
      size_t off = (size_t)(wave * 16 + n16) * C_ + kk * 32 + quad * 8;
      Ah = *(const bf16x8f*)(const void*)(wqkh + off);
      Al = *(const bf16x8f*)(const void*)(wqkl + off);
    }
#pragma unroll
    for (int nt = 0; nt < 2; nt++) {
      size_t off = ((size_t)b * N_ + nb + nt * 16 + n16) * C_ + kk * 32 + quad * 8;
      Bh[nt] = *(const bf16x8f*)(const void*)(xthi + off);
      Bl[nt] = *(const bf16x8f*)(const void*)(xtlo + off);
    }
#pragma unroll
    for (int nt = 0; nt < 2; nt++) {
      acc[nt] = __builtin_amdgcn_mfma_f32_16x16x32_bf16(Ah, Bh[nt], acc[nt], 0, 0, 0);
      acc[nt] = __builtin_amdgcn_mfma_f32_16x16x32_bf16(Al, Bh[nt], acc[nt], 0, 0, 0);
      acc[nt] = __builtin_amdgcn_mfma_f32_16x16x32_bf16(Ah, Bl[nt], acc[nt], 0, 0, 0);
    }
  }
#pragma unroll
  for (int nt = 0; nt < 2; nt++) {
    int n = nb + nt * 16 + n16;
    int o0 = (wave & 1) * 16 + quad * 4;       // o within q or k (0..31)
    bf4pack ph, pl;
#pragma unroll
    for (int r = 0; r < 4; r++) {
      float v = acc[nt][r] + (wave < 2 ? bq[o0 + r] : bk[o0 + r]);
      bf16 h = __float2bfloat16(v);
      ph.h[r] = h; pl.h[r] = __float2bfloat16(v - __bfloat162float(h));
    }
    size_t base = ((size_t)b * N_ + n) * QK_ + o0;
    if (wave < 2) { *(uint2*)(qhi + base) = ph.u; *(uint2*)(qlo + base) = pl.u; }
    else          { *(uint2*)(khi + base) = ph.u; *(uint2*)(klo + base) = pl.u; }
  }
}

// ---- k_vbf2: V proj via MFMA. A=wv (rows c), B=xT (rows n), K=256 ----
__global__ __launch_bounds__(256) void k_vbf2(
    const bf16* __restrict__ xthi, const bf16* __restrict__ xtlo,
    const bf16* __restrict__ wvh, const bf16* __restrict__ wvl,
    const float* __restrict__ bv, bf16* __restrict__ vbf) {
  int b = blockIdx.y;
  int n0 = blockIdx.x * 32;
  int tid = threadIdx.x;
  int lane = tid & 63, wave = tid >> 6;
  int n16 = lane & 15, quad = lane >> 4;
  int c0 = wave * 64;

  f32x4 acc[4][2];                              // [ct][nt]
#pragma unroll
  for (int ct = 0; ct < 4; ct++)
#pragma unroll
    for (int nt = 0; nt < 2; nt++) acc[ct][nt] = (f32x4)(0.f);

#pragma unroll
  for (int kk = 0; kk < 8; kk++) {
    bf16x8f Ah[4], Al[4], Bh[2], Bl[2];
#pragma unroll
    for (int ct = 0; ct < 4; ct++) {
      size_t off = (size_t)(c0 + ct * 16 + n16) * C_ + kk * 32 + quad * 8;
      Ah[ct] = *(const bf16x8f*)(const void*)(wvh + off);
      Al[ct] = *(const bf16x8f*)(const void*)(wvl + off);
    }
#pragma unroll
    for (int nt = 0; nt < 2; nt++) {
      size_t off = ((size_t)b * N_ + n0 + nt * 16 + n16) * C_ + kk * 32 + quad * 8;
      Bh[nt] = *(const bf16x8f*)(const void*)(xthi + off);
      Bl[nt] = *(const bf16x8f*)(const void*)(xtlo + off);
    }
#pragma unroll
    for (int ct = 0; ct < 4; ct++)
#pragma unroll
      for (int nt = 0; nt < 2; nt++) {
        acc[ct][nt] = __builtin_amdgcn_mfma_f32_16x16x32_bf16(Ah[ct], Bh[nt], acc[ct][nt], 0, 0, 0);
        acc[ct][nt] = __builtin_amdgcn_mfma_f32_16x16x32_bf16(Al[ct], Bh[nt], acc[ct][nt], 0, 0, 0);
        acc[ct][nt] = __builtin_amdgcn_mfma_f32_16x16x32_bf16(Ah[ct], Bl[nt], acc[ct][nt], 0, 0, 0);
      }
  }
#pragma unroll
  for (int ct = 0; ct < 4; ct++)
#pragma unroll
    for (int nt = 0; nt < 2; nt++) {
      int n = n0 + nt * 16 + n16;
      int cb = c0 + ct * 16 + quad * 4;
#pragma unroll
      for (int r = 0; r < 4; r++) {
        float v = acc[ct][nt][r] + bv[cb + r];
        vbf[((size_t)b * C_ + cb + r) * N_ + n] = __float2bfloat16(v);
      }
    }
}

// ---- k_pbm v16: 16 phases x 2 j-tiles per barrier; 4 bufs, pitch 128,
//      rotation swizzle; flash-no-max. pamT bit-identical to R29/R33. ----
__global__ __launch_bounds__(512) void k_pbm(
    const bf16* __restrict__ qhi, const bf16* __restrict__ qlo,
    const bf16* __restrict__ khi, const bf16* __restrict__ klo,
    const bf16* __restrict__ vbf,
    float* __restrict__ pamT) {
  int b = blockIdx.z;
  int h0 = blockIdx.y * 128;                     // channel half
  int i0 = blockIdx.x * 64;
  int tid = threadIdx.x;
  int lane = tid & 63, wave = tid >> 6;
  int n16 = lane & 15, quad = lane >> 4;

  __shared__ __align__(16) bf16 p_s[4][64 * 128];   // 65536 B exactly

  bf16x8f ahf[4], alf[4];
#pragma unroll
  for (int ih = 0; ih < 4; ih++) {
    size_t qoff = ((size_t)b * N_ + i0 + ih * 16 + n16) * QK_ + quad * 8;
    ahf[ih] = *(const bf16x8f*)(const void*)(qhi + qoff);
    alf[ih] = *(const bf16x8f*)(const void*)(qlo + qoff);
  }

  f32x4 acc[4];
  float l16[16];
#pragma unroll
  for (int ih = 0; ih < 4; ih++) acc[ih] = (f32x4)(0.f);
#pragma unroll
  for (int k = 0; k < 16; k++) l16[k] = 0.f;

  const bf16* khb = khi + ((size_t)b * N_ + wave * 16 + n16) * QK_ + quad * 8;
  const bf16* klb = klo + ((size_t)b * N_ + wave * 16 + n16) * QK_ + quad * 8;
  const bf16* vb0 = vbf + ((size_t)b * C_ + h0 + wave * 16 + n16) * N_ + quad * 8;

  const int NPH = 16;                            // phases; 2 tiles each
  int wcol = wave * 16 + n16;
  int wblk = wcol >> 3, wrem = wcol & 7;

  // ---- prologue: produce P tiles 0,1 into bufs 0,1; prefetch K 2,3; V 0,1 ----
  bf16x8f khf[2], klf[2];
#pragma unroll
  for (int tt = 0; tt < 2; tt++) {
    khf[tt] = *(const bf16x8f*)(const void*)(khb + (size_t)tt * TJ_ * QK_);
    klf[tt] = *(const bf16x8f*)(const void*)(klb + (size_t)tt * TJ_ * QK_);
  }
#pragma unroll
  for (int tt = 0; tt < 2; tt++) {
    bf16* pbuf = p_s[tt];
#pragma unroll
    for (int ih = 0; ih < 4; ih++) {
      f32x4 t = (f32x4)(0.f);
      t = __builtin_amdgcn_mfma_f32_16x16x32_bf16(ahf[ih], khf[tt], t, 0, 0, 0);
      t = __builtin_amdgcn_mfma_f32_16x16x32_bf16(alf[ih], khf[tt], t, 0, 0, 0);
      t = __builtin_amdgcn_mfma_f32_16x16x32_bf16(ahf[ih], klf[tt], t, 0, 0, 0);
#pragma unroll
      for (int r = 0; r < 4; r++) {
        int i = ih * 16 + quad * 4 + r;
        float p = __expf(t[r]);
        l16[ih * 4 + r] += p;
        pbuf[i * 128 + (((wblk + i) & 15) << 3) + wrem] = __float2bfloat16(p);
      }
    }
  }
#pragma unroll
  for (int tt = 0; tt < 2; tt++) {
    khf[tt] = *(const bf16x8f*)(const void*)(khb + (size_t)(2 + tt) * TJ_ * QK_);
    klf[tt] = *(const bf16x8f*)(const void*)(klb + (size_t)(2 + tt) * TJ_ * QK_);
  }
  bf16x8f vcur[2][4];
#pragma unroll
  for (int tt = 0; tt < 2; tt++)
#pragma unroll
    for (int jhh = 0; jhh < 4; jhh++)
      vcur[tt][jhh] = *(const bf16x8f*)(const void*)(vb0 + (size_t)tt * TJ_ + jhh * 32);
  __syncthreads();                               // P(0),P(1) visible

  for (int t = 0; t < NPH; t++) {
    int pp = t & 1;
    bf16* consume0 = p_s[pp * 2];
    bf16* consume1 = p_s[pp * 2 + 1];
    bf16* produce0 = p_s[(pp ^ 1) * 2];
    bf16* produce1 = p_s[(pp ^ 1) * 2 + 1];
    bool have_next = (t + 1 < NPH);

#pragma unroll
    for (int tt = 0; tt < 2; tt++) {
      const bf16* cbuf = (tt == 0) ? consume0 : consume1;
      bf16* pbuf = (tt == 0) ? produce0 : produce1;
      // QK for tile 2(t+1)+tt
      f32x4 z[4];
      if (have_next) {
#pragma unroll
        for (int ih = 0; ih < 4; ih++) {
          f32x4 zz = (f32x4)(0.f);
          zz = __builtin_amdgcn_mfma_f32_16x16x32_bf16(ahf[ih], khf[tt], zz, 0, 0, 0);
          zz = __builtin_amdgcn_mfma_f32_16x16x32_bf16(alf[ih], khf[tt], zz, 0, 0, 0);
          zz = __builtin_amdgcn_mfma_f32_16x16x32_bf16(ahf[ih], klf[tt], zz, 0, 0, 0);
          z[ih] = zz;
        }
      }
      // PV for tile 2t+tt (swizzled reads)
#pragma unroll
      for (int jhh = 0; jhh < 4; jhh++) {
        int jb = jhh * 4 + quad;
        bf16x8f pa[4];
#pragma unroll
        for (int ih = 0; ih < 4; ih++) {
          int ir = ih * 16 + n16;
          pa[ih] = *(const bf16x8f*)(const void*)(cbuf + ir * 128 + (((jb + ir) & 15) << 3));
        }
#pragma unroll
        for (int ih = 0; ih < 4; ih++)
          acc[ih] = __builtin_amdgcn_mfma_f32_16x16x32_bf16(pa[ih], vcur[tt][jhh], acc[ih], 0, 0, 0);
      }
      // exp -> write P for tile 2(t+1)+tt
      if (have_next) {
#pragma unroll
        for (int ih = 0; ih < 4; ih++)
#pragma unroll
          for (int r = 0; r < 4; r++) {
            int i = ih * 16 + quad * 4 + r;
            float p = __expf(z[ih][r]);
            l16[ih * 4 + r] += p;
            pbuf[i * 128 + (((wblk + i) & 15) << 3) + wrem] = __float2bfloat16(p);
          }
      }
    }
    // prefetch K (tiles 2(t+2)+tt), V (tiles 2(t+1)+tt)
    bf16x8f khn[2], kln[2], vnxt[2][4];
    if (t + 2 < NPH) {
#pragma unroll
      for (int tt = 0; tt < 2; tt++) {
        size_t koff = (size_t)(2 * (t + 2) + tt) * TJ_ * QK_;
        khn[tt] = *(const bf16x8f*)(const void*)(khb + koff);
        kln[tt] = *(const bf16x8f*)(const void*)(klb + koff);
      }
    }
    if (have_next) {
#pragma unroll
      for (int tt = 0; tt < 2; tt++) {
        size_t vb = (size_t)(2 * (t + 1) + tt) * TJ_;
#pragma unroll
        for (int jhh = 0; jhh < 4; jhh++)
          vnxt[tt][jhh] = *(const bf16x8f*)(const void*)(vb0 + vb + jhh * 32);
      }
    }
    __syncthreads();                             // produce visible; consume done
#pragma unroll
    for (int tt = 0; tt < 2; tt++) {
      khf[tt] = khn[tt]; klf[tt] = kln[tt];
#pragma unroll
      for (int jhh = 0; jhh < 4; jhh++) vcur[tt][jhh] = vnxt[tt][jhh];
    }
  }

  // ---- epilogue: reduce l over 16 n16-lanes, then 8 waves; scale+store ----
#pragma unroll
  for (int d = 1; d < 16; d <<= 1)
#pragma unroll
    for (int k = 0; k < 16; k++)
      l16[k] += __shfl_xor(l16[k], d, 64);
  float* red = (float*)p_s;                      // aliases bufs 0/1 (safe after final barrier)
  float* linv = red + 8 * 64;
  if (n16 == 0) {
#pragma unroll
    for (int ih = 0; ih < 4; ih++)
#pragma unroll
      for (int r = 0; r < 4; r++)
        red[wave * 64 + ih * 16 + quad * 4 + r] = l16[ih * 4 + r];
  }
  __syncthreads();
  if (tid < 64) {
    float L = 0.f;
#pragma unroll
    for (int w = 0; w < 8; w++) L += red[w * 64 + tid];
    linv[tid] = 1.0f / L;
  }
  __syncthreads();
  int c = h0 + wave * 16 + n16;
#pragma unroll
  for (int ih = 0; ih < 4; ih++)
#pragma unroll
    for (int r = 0; r < 4; r++) {
      int i = ih * 16 + quad * 4 + r;
      pamT[((size_t)b * N_ + i0 + i) * C_ + c] = acc[ih][r] * linv[i];
    }
}

// ---- k_ce2 v2: j-half split -> 256 blocks; per-block traffic 320 KB ----
__global__ __launch_bounds__(256) void k_ce2(
    const bf16* __restrict__ xchi, const bf16* __restrict__ xclo,
    float* __restrict__ eCp) {
  int b = blockIdx.z;
  int kc = blockIdx.y;
  int it = blockIdx.x & 7, jh = blockIdx.x >> 3;
  int i0 = it * 32;
  int tid = threadIdx.x;
  int lane = tid & 63, wave = tid >> 6;
  int n16 = lane & 15, quad = lane >> 4;
  int j0 = jh * 128 + wave * 32;

  f32x4 acc[2][2];                               // [it2][jt]
#pragma unroll
  for (int it2 = 0; it2 < 2; it2++)
#pragma unroll
    for (int jt = 0; jt < 2; jt++) acc[it2][jt] = (f32x4)(0.f);

  size_t kb = (size_t)kc * 512;
#pragma unroll 2
  for (int kk = 0; kk < 16; kk++) {
    bf16x8f Ah[2], Al[2], Bh[2], Bl[2];
#pragma unroll
    for (int it2 = 0; it2 < 2; it2++) {
      size_t off = ((size_t)b * C_ + i0 + it2 * 16 + n16) * N_ + kb + kk * 32 + quad * 8;
      Ah[it2] = *(const bf16x8f*)(const void*)(xchi + off);
      Al[it2] = *(const bf16x8f*)(const void*)(xclo + off);
    }
#pragma unroll
    for (int jt = 0; jt < 2; jt++) {
      size_t off = ((size_t)b * C_ + j0 + jt * 16 + n16) * N_ + kb + kk * 32 + quad * 8;
      Bh[jt] = *(const bf16x8f*)(const void*)(xchi + off);
      Bl[jt] = *(const bf16x8f*)(const void*)(xclo + off);
    }
#pragma unroll
    for (int it2 = 0; it2 < 2; it2++)
#pragma unroll
      for (int jt = 0; jt < 2; jt++) {
        acc[it2][jt] = __builtin_amdgcn_mfma_f32_16x16x32_bf16(Ah[it2], Bh[jt], acc[it2][jt], 0, 0, 0);
        acc[it2][jt] = __builtin_amdgcn_mfma_f32_16x16x32_bf16(Al[it2], Bh[jt], acc[it2][jt], 0, 0, 0);
        acc[it2][jt] = __builtin_amdgcn_mfma_f32_16x16x32_bf16(Ah[it2], Bl[jt], acc[it2][jt], 0, 0, 0);
      }
  }
  float* dst = eCp + ((size_t)kc * B_ + b) * C_ * C_;
#pragma unroll
  for (int it2 = 0; it2 < 2; it2++)
#pragma unroll
    for (int jt = 0; jt < 2; jt++) {
      int i = i0 + it2 * 16 + quad * 4;
      int j = j0 + jt * 16 + n16;
#pragma unroll
      for (int r = 0; r < 4; r++)
        dst[(size_t)(i + r) * C_ + j] = acc[it2][jt][r];
    }
}

// ---- k_cs v4: CAM softmax over -e; emit bf16 hi ONLY ----
__global__ __launch_bounds__(256) void k_cs(
    const float* __restrict__ eCp, bf16* __restrict__ ahi) {
  int row = blockIdx.x;
  int b = row >> 8, i = row & 255;
  int j = threadIdx.x;
  float e = 0.f;
#pragma unroll
  for (int kc = 0; kc < 8; kc++) e += eCp[(((size_t)kc * B_ + b) * C_ + i) * C_ + j];
  float ne = -e;
  __shared__ float buf[256];
  buf[j] = ne;
  __syncthreads();
  for (int st = 128; st >= 1; st >>= 1) {
    if (j < st) buf[j] = fmaxf(buf[j], buf[j + st]);
    __syncthreads();
  }
  float m = buf[0];
  __syncthreads();
  float p = __expf(ne - m);
  buf[j] = p;
  __syncthreads();
  for (int st = 128; st >= 1; st >>= 1) {
    if (j < st) buf[j] += buf[j + st];
    __syncthreads();
  }
  ahi[(size_t)row * C_ + j] = __float2bfloat16(p / buf[0]);
}

// ---- k_cam v5: hi-only (1 MFMA); fused out = gp*pamT + gc*cam + 2x ----
__global__ __launch_bounds__(512) void k_cam(
    const bf16* __restrict__ xthi,
    const bf16* __restrict__ ahi,
    const float* __restrict__ pamT, const float* __restrict__ x,
    const float* __restrict__ gpam, const float* __restrict__ gcam,
    float* __restrict__ out) {
  int b = blockIdx.y;
  int n0 = blockIdx.x * 32;
  int tid = threadIdx.x;
  int lane = tid & 63, wave = tid >> 6;
  int n16 = lane & 15, quad = lane >> 4;
  int c0 = wave * 32;

  f32x4 acc[2][2];                               // [nt][ct]
#pragma unroll
  for (int nt = 0; nt < 2; nt++)
#pragma unroll
    for (int ct = 0; ct < 2; ct++) acc[nt][ct] = (f32x4)(0.f);

#pragma unroll
  for (int kk = 0; kk < 8; kk++) {               // K = 256 = 8 x 32
    bf16x8f Ah[2], Bh[2];
#pragma unroll
    for (int nt = 0; nt < 2; nt++) {
      size_t off = ((size_t)b * N_ + n0 + nt * 16 + n16) * C_ + kk * 32 + quad * 8;
      Ah[nt] = *(const bf16x8f*)(const void*)(xthi + off);
    }
#pragma unroll
    for (int ct = 0; ct < 2; ct++) {
      size_t off = ((size_t)b * C_ + c0 + ct * 16 + n16) * C_ + kk * 32 + quad * 8;
      Bh[ct] = *(const bf16x8f*)(const void*)(ahi + off);
    }
#pragma unroll
    for (int nt = 0; nt < 2; nt++)
#pragma unroll
      for (int ct = 0; ct < 2; ct++)
        acc[nt][ct] = __builtin_amdgcn_mfma_f32_16x16x32_bf16(Ah[nt], Bh[ct], acc[nt][ct], 0, 0, 0);
  }
  float gp = gpam[0], gc = gcam[0];
#pragma unroll
  for (int nt = 0; nt < 2; nt++)
#pragma unroll
    for (int ct = 0; ct < 2; ct++) {
      int c = c0 + ct * 16 + n16;
      int nb = n0 + nt * 16 + quad * 4;
      const float* xp = x + ((size_t)b * C_ + c) * N_ + nb;
      float4 x4 = *(const float4*)(const void*)xp;
      float4 o4;
      o4.x = gp * pamT[((size_t)b * N_ + nb + 0) * C_ + c] + gc * acc[nt][ct][0] + 2.0f * x4.x;
      o4.y = gp * pamT[((size_t)b * N_ + nb + 1) * C_ + c] + gc * acc[nt][ct][1] + 2.0f * x4.y;
      o4.z = gp * pamT[((size_t)b * N_ + nb + 2) * C_ + c] + gc * acc[nt][ct][2] + 2.0f * x4.z;
      o4.w = gp * pamT[((size_t)b * N_ + nb + 3) * C_ + c] + gc * acc[nt][ct][3] + 2.0f * x4.w;
      *(float4*)(out + ((size_t)b * C_ + c) * N_ + nb) = o4;
    }
}

extern "C" void kernel_launch(void* const* d_in, const int* in_sizes, int n_in,
                              void* d_out, int out_size, void* d_ws, size_t ws_size,
                              hipStream_t stream) {
  const float* x  = (const float*)d_in[0];
  const float* wq = (const float*)d_in[1];
  const float* bq = (const float*)d_in[2];
  const float* wk = (const float*)d_in[3];
  const float* bk = (const float*)d_in[4];
  const float* wv = (const float*)d_in[5];
  const float* bv = (const float*)d_in[6];
  const float* gp = (const float*)d_in[7];
  const float* gc = (const float*)d_in[8];
  float* out = (float*)d_out;

  float* ws = (float*)d_ws;
  size_t o = 0;
  float* pamT  = ws + o; o += (size_t)B_ * N_ * C_;     // 2097152
  float* mp    = ws + o; o += (size_t)2 * B_ * N_;      // 16384 (unused, layout kept)
  float* lp    = ws + o; o += (size_t)2 * B_ * N_;      // 16384 (unused, layout kept)
  float* eCp   = ws + o; o += (size_t)8 * B_ * C_ * C_; // 1048576
  bf16*  ahi   = (bf16*)(ws + o); o += (size_t)B_ * C_ * C_ / 2;   // 65536 fl
  bf16*  alo   = (bf16*)(ws + o); o += (size_t)B_ * C_ * C_ / 2;   // 65536 fl (unused)
  bf16*  vbf   = (bf16*)(ws + o); o += (size_t)B_ * N_ * C_ / 2;   // 1048576
  bf16*  qhi   = (bf16*)(ws + o); o += (size_t)B_ * N_ * QK_ / 2;  // 131072
  bf16*  qlo   = (bf16*)(ws + o); o += (size_t)B_ * N_ * QK_ / 2;  // 131072
  bf16*  khi   = (bf16*)(ws + o); o += (size_t)B_ * N_ * QK_ / 2;  // 131072
  bf16*  klo   = (bf16*)(ws + o); o += (size_t)B_ * N_ * QK_ / 2;  // 131072
  float* xtbuf = ws + o; o += (size_t)2 * B_ * N_ * QK_ * 4;       // 2097152 (xT hi/lo)
  bf16* xthi = (bf16*)xtbuf;
  bf16* xtlo = (bf16*)(xtbuf + (size_t)B_ * N_ * C_ / 2);
  // weight hi/lo buffers alias eCp (dead until k_ce2; k_qkp/k_vbf2 run first)
  bf16* wqkh = (bf16*)eCp;
  bf16* wqkl = wqkh + (size_t)64 * C_;
  bf16* wvh  = wqkl + (size_t)64 * C_;
  bf16* wvl  = wvh + (size_t)C_ * C_;
  // x [b][c][n] hi/lo alias pamT (dead until k_pbm; k_ce2/k_cs run before)
  bf16* xchi = (bf16*)pamT;
  bf16* xclo = xchi + (size_t)B_ * C_ * N_;     // 2x 1M floats = exact fit
  (void)mp; (void)lp; (void)alo;
  // total ~6.8 M floats = 27.4 MB (unchanged)

  k_wcv<<<dim3((64 * C_ + C_ * C_) / 256), dim3(256), 0, stream>>>(wq, wk, wv, wqkh, wqkl, wvh, wvl);
  k_xt<<<dim3(N_ / 64, C_ / 64, B_), dim3(256), 0, stream>>>(x, xthi, xtlo, xchi, xclo);
  k_qkp<<<dim3(N_ / 32, B_), dim3(256), 0, stream>>>(xthi, xtlo, wqkh, wqkl, bq, bk, qhi, qlo, khi, klo);
  k_vbf2<<<dim3(N_ / 32, B_), dim3(256), 0, stream>>>(xthi, xtlo, wvh, wvl, bv, vbf);
  k_ce2<<<dim3(16, 8, B_), dim3(256), 0, stream>>>(xchi, xclo, eCp);
  k_cs<<<dim3(B_ * C_), dim3(256), 0, stream>>>(eCp, ahi);
  k_pbm<<<dim3(N_ / 64, 2, B_), dim3(512), 0, stream>>>(qhi, qlo, khi, klo, vbf, pamT);
  k_cam<<<dim3(N_ / 32, B_), dim3(512), 0, stream>>>(xthi, ahi, pamT, x, gp, gc, out);
}